// Round 3
// baseline (82.857 us; speedup 1.0000x reference)
//
#include <hip/hip_runtime.h>
#include <cstddef>
#include <cstdint>

// B=256, S=16384, R=16, N=6.
//   V_k[b,(d,e)] = sum_s z[b,s]*core_k[d,s,e]  (k=1..5) -> bf16-split MFMA GEMM
//   W[b] = V1..V5 chain; out[b,s] = sum_d c0[s,d]*W[b,d]
namespace {
constexpr int kB = 256;
constexpr int kS = 16384;
constexpr int kNCol = 1040;   // 4 cores * 256 + 16 (core5)
constexpr int BK = 64;
}

using short8  = __attribute__((ext_vector_type(8))) short;   // 8 bf16
using f32x4   = __attribute__((ext_vector_type(4))) float;
using f32x16  = __attribute__((ext_vector_type(16))) float;

// truncation split: x ~= hi + lo (bf16 each)
__device__ __forceinline__ void cvt4(float x0, float x1, float x2, float x3,
                                     ushort4& h, ushort4& l) {
    uint32_t u0 = __float_as_uint(x0), u1 = __float_as_uint(x1),
             u2 = __float_as_uint(x2), u3 = __float_as_uint(x3);
    h.x = (unsigned short)(u0 >> 16); h.y = (unsigned short)(u1 >> 16);
    h.z = (unsigned short)(u2 >> 16); h.w = (unsigned short)(u3 >> 16);
    float r0 = x0 - __uint_as_float(u0 & 0xffff0000u);
    float r1 = x1 - __uint_as_float(u1 & 0xffff0000u);
    float r2 = x2 - __uint_as_float(u2 & 0xffff0000u);
    float r3 = x3 - __uint_as_float(u3 & 0xffff0000u);
    l.x = (unsigned short)(__float_as_uint(r0) >> 16);
    l.y = (unsigned short)(__float_as_uint(r1) >> 16);
    l.z = (unsigned short)(__float_as_uint(r2) >> 16);
    l.w = (unsigned short)(__float_as_uint(r3) >> 16);
}

__device__ __forceinline__ void cvt8(const float4& a, const float4& b,
                                     short8& h, short8& l) {
    float x[8] = {a.x, a.y, a.z, a.w, b.x, b.y, b.z, b.w};
    #pragma unroll
    for (int i = 0; i < 8; ++i) {
        uint32_t u = __float_as_uint(x[i]);
        h[i] = (short)(u >> 16);
        float r = x[i] - __uint_as_float(u & 0xffff0000u);
        l[i] = (short)(__float_as_uint(r) >> 16);
    }
}

// ---------------------------------------------------------------------------
// GEMM: vp[sk][b][col] partial of z @ G over k-chunk sk.
// grid flat = 18*splitk: (sk, mt, ct); ct 0..7 full (128 cols), ct 8 = core5.
// Block 256 thr = 4 waves 2x2, tile 128b x 128n, BK=64, 32x32x16 MFMA,
// 3-term bf16 split (hi*hi + hi*lo + lo*hi).
// LDS: [plane][row/col][64] bf16, XOR swizzle kx = k ^ ((row&7)<<3).
// ---------------------------------------------------------------------------
__global__ __launch_bounds__(256, 2) void fttv_gemm_mfma(
    const float* __restrict__ z,
    const float* __restrict__ c1, const float* __restrict__ c2,
    const float* __restrict__ c3, const float* __restrict__ c4,
    const float* __restrict__ c5,
    float* __restrict__ vp, int kc)
{
    __shared__ __align__(16) unsigned short As[2 * 128 * 64];   // 32 KB
    __shared__ __align__(16) unsigned short Bs[2 * 128 * 64];   // 32 KB

    // bijective XCD swizzle
    const int nwg = gridDim.x;
    const int q = nwg >> 3, r = nwg & 7;
    const int xcd = blockIdx.x & 7, rest = blockIdx.x >> 3;
    const int vfl = (xcd < r ? xcd * (q + 1) : r * (q + 1) + (xcd - r) * q) + rest;
    const int sk = vfl / 18;
    const int rem = vfl - sk * 18;
    const int mt = rem / 9;
    const int ct = rem - mt * 9;

    const int tid = threadIdx.x;
    const int w = tid >> 6, l = tid & 63;
    const int wm = w >> 1, wn = w & 1;
    const int b0 = mt * 128;
    const int sbeg = sk * kc;

    // A staging: thread -> row=tid>>1, 32 consecutive k at (tid&1)*32
    const int arow = tid >> 1;
    const int ak0 = (tid & 1) * 32;
    const float* zp = z + (size_t)(b0 + arow) * kS + sbeg + ak0;
    const int aswz = (arow & 7) << 3;

    if (ct < 8) {
        const int ci = ct >> 1;
        const float* cp = (ci == 0 ? c1 : ci == 1 ? c2 : ci == 2 ? c3 : c4);
        // B staging: thread -> 8 cols (bn0..+7), 4 k (bk0..+3)
        const int bn0 = (tid >> 4) * 8;
        const int bk0 = (tid & 15) * 4;
        const int off = (ct & 1) * 128 + bn0;     // col within core, mult of 8
        const int d0 = off >> 4, e0 = off & 15;   // e0 in {0,8}
        const float* bp = cp + (size_t)d0 * kS * 16 + e0;

        f32x16 acc[2][2];
        #pragma unroll
        for (int i = 0; i < 2; ++i)
            #pragma unroll
            for (int j = 0; j < 2; ++j)
                #pragma unroll
                for (int t = 0; t < 16; ++t) acc[i][j][t] = 0.f;

        float4 za[8], bb0[4], bb1[4];
        #pragma unroll
        for (int p = 0; p < 8; ++p)
            za[p] = *reinterpret_cast<const float4*>(zp + 4 * p);
        #pragma unroll
        for (int j = 0; j < 4; ++j) {
            const size_t so = (size_t)(sbeg + bk0 + j) * 16;
            bb0[j] = *reinterpret_cast<const float4*>(bp + so);
            bb1[j] = *reinterpret_cast<const float4*>(bp + so + 4);
        }

        for (int sb = 0; sb < kc; sb += BK) {
            // commit A (4 x b128 per plane)
            #pragma unroll
            for (int p2 = 0; p2 < 4; ++p2) {
                short8 h, lo;
                cvt8(za[2 * p2], za[2 * p2 + 1], h, lo);
                const int kx = (ak0 + p2 * 8) ^ aswz;
                *reinterpret_cast<short8*>(&As[arow * 64 + kx]) = h;
                *reinterpret_cast<short8*>(&As[8192 + arow * 64 + kx]) = lo;
            }
            // commit B (per col: ushort4 over 4 k)
            #pragma unroll
            for (int j = 0; j < 8; ++j) {
                const float4* src = (j < 4) ? bb0 : bb1;
                const int jj = j & 3;
                ushort4 h, lo;
                cvt4(src[0][jj], src[1][jj], src[2][jj], src[3][jj], h, lo);
                const int col = bn0 + j;
                const int kx = bk0 ^ ((col & 7) << 3);
                *reinterpret_cast<ushort4*>(&Bs[col * 64 + kx]) = h;
                *reinterpret_cast<ushort4*>(&Bs[8192 + col * 64 + kx]) = lo;
            }
            __syncthreads();
            if (sb + BK < kc) {   // prefetch next stage under MFMA
                const int sn = sb + BK;
                #pragma unroll
                for (int p = 0; p < 8; ++p)
                    za[p] = *reinterpret_cast<const float4*>(zp + sn + 4 * p);
                #pragma unroll
                for (int j = 0; j < 4; ++j) {
                    const size_t so = (size_t)(sbeg + sn + bk0 + j) * 16;
                    bb0[j] = *reinterpret_cast<const float4*>(bp + so);
                    bb1[j] = *reinterpret_cast<const float4*>(bp + so + 4);
                }
            }
            #pragma unroll
            for (int ks = 0; ks < 4; ++ks) {
                const int kf = ks * 16 + (l >> 5) * 8;
                short8 ah[2], alo[2], bh[2], blo[2];
                #pragma unroll
                for (int fm = 0; fm < 2; ++fm) {
                    const int row = wm * 64 + fm * 32 + (l & 31);
                    const int kx = kf ^ ((row & 7) << 3);
                    ah[fm]  = *reinterpret_cast<const short8*>(&As[row * 64 + kx]);
                    alo[fm] = *reinterpret_cast<const short8*>(&As[8192 + row * 64 + kx]);
                }
                #pragma unroll
                for (int fn = 0; fn < 2; ++fn) {
                    const int col = wn * 64 + fn * 32 + (l & 31);
                    const int kx = kf ^ ((col & 7) << 3);
                    bh[fn]  = *reinterpret_cast<const short8*>(&Bs[col * 64 + kx]);
                    blo[fn] = *reinterpret_cast<const short8*>(&Bs[8192 + col * 64 + kx]);
                }
                #pragma unroll
                for (int fm = 0; fm < 2; ++fm)
                    #pragma unroll
                    for (int fn = 0; fn < 2; ++fn) {
                        acc[fm][fn] = __builtin_amdgcn_mfma_f32_32x32x16_bf16(
                            ah[fm], bh[fn], acc[fm][fn], 0, 0, 0);
                        acc[fm][fn] = __builtin_amdgcn_mfma_f32_32x32x16_bf16(
                            ah[fm], blo[fn], acc[fm][fn], 0, 0, 0);
                        acc[fm][fn] = __builtin_amdgcn_mfma_f32_32x32x16_bf16(
                            alo[fm], bh[fn], acc[fm][fn], 0, 0, 0);
                    }
            }
            __syncthreads();
        }
        // epilogue: D layout col=l&31, row=(q&3)+8*(q>>2)+4*(l>>5)
        #pragma unroll
        for (int fm = 0; fm < 2; ++fm)
            #pragma unroll
            for (int fn = 0; fn < 2; ++fn) {
                const int rb = b0 + wm * 64 + fm * 32 + 4 * (l >> 5);
                const int col = ct * 128 + wn * 64 + fn * 32 + (l & 31);
                #pragma unroll
                for (int qq = 0; qq < 16; ++qq) {
                    const int b = rb + (qq & 3) + 8 * (qq >> 2);
                    vp[((size_t)sk * kB + b) * kNCol + col] = acc[fm][fn][qq];
                }
            }
    } else {
        // core5 runt: 16 cols, 16x16x32 MFMA; wave w -> rows w*32..+31
        const int col5 = tid >> 4;        // 0..15
        const int k05 = (tid & 15) * 4;
        const float* bp = c5 + (size_t)col5 * kS + sbeg + k05;

        f32x4 acc4[2];
        #pragma unroll
        for (int i = 0; i < 2; ++i) acc4[i] = (f32x4){0.f, 0.f, 0.f, 0.f};

        float4 za[8], bz;
        #pragma unroll
        for (int p = 0; p < 8; ++p)
            za[p] = *reinterpret_cast<const float4*>(zp + 4 * p);
        bz = *reinterpret_cast<const float4*>(bp);

        for (int sb = 0; sb < kc; sb += BK) {
            #pragma unroll
            for (int p2 = 0; p2 < 4; ++p2) {
                short8 h, lo;
                cvt8(za[2 * p2], za[2 * p2 + 1], h, lo);
                const int kx = (ak0 + p2 * 8) ^ aswz;
                *reinterpret_cast<short8*>(&As[arow * 64 + kx]) = h;
                *reinterpret_cast<short8*>(&As[8192 + arow * 64 + kx]) = lo;
            }
            {
                ushort4 h, lo;
                cvt4(bz.x, bz.y, bz.z, bz.w, h, lo);
                const int kx = k05 ^ ((col5 & 7) << 3);
                *reinterpret_cast<ushort4*>(&Bs[col5 * 64 + kx]) = h;
                *reinterpret_cast<ushort4*>(&Bs[8192 + col5 * 64 + kx]) = lo;
            }
            __syncthreads();
            if (sb + BK < kc) {
                const int sn = sb + BK;
                #pragma unroll
                for (int p = 0; p < 8; ++p)
                    za[p] = *reinterpret_cast<const float4*>(zp + sn + 4 * p);
                bz = *reinterpret_cast<const float4*>(bp + sn);
            }
            #pragma unroll
            for (int kb = 0; kb < 2; ++kb) {
                const int kf = kb * 32 + (l >> 4) * 8;
                short8 ah[2], alo[2], bh, blo;
                #pragma unroll
                for (int fm = 0; fm < 2; ++fm) {
                    const int row = w * 32 + fm * 16 + (l & 15);
                    const int kx = kf ^ ((row & 7) << 3);
                    ah[fm]  = *reinterpret_cast<const short8*>(&As[row * 64 + kx]);
                    alo[fm] = *reinterpret_cast<const short8*>(&As[8192 + row * 64 + kx]);
                }
                {
                    const int cc = l & 15;
                    const int kx = kf ^ ((cc & 7) << 3);
                    bh  = *reinterpret_cast<const short8*>(&Bs[cc * 64 + kx]);
                    blo = *reinterpret_cast<const short8*>(&Bs[8192 + cc * 64 + kx]);
                }
                #pragma unroll
                for (int fm = 0; fm < 2; ++fm) {
                    acc4[fm] = __builtin_amdgcn_mfma_f32_16x16x32_bf16(
                        ah[fm], bh, acc4[fm], 0, 0, 0);
                    acc4[fm] = __builtin_amdgcn_mfma_f32_16x16x32_bf16(
                        ah[fm], blo, acc4[fm], 0, 0, 0);
                    acc4[fm] = __builtin_amdgcn_mfma_f32_16x16x32_bf16(
                        alo[fm], bh, acc4[fm], 0, 0, 0);
                }
            }
            __syncthreads();
        }
        #pragma unroll
        for (int fm = 0; fm < 2; ++fm) {
            const int rb = b0 + w * 32 + fm * 16 + (l >> 4) * 4;
            const int col = 1024 + (l & 15);
            #pragma unroll
            for (int qq = 0; qq < 4; ++qq)
                vp[((size_t)sk * kB + rb + qq) * kNCol + col] = acc4[fm][qq];
        }
    }
}

// ---------------------------------------------------------------------------
// v[b][col] = sum_sk vp[sk][b][col]   (fully coalesced)
__global__ void fttv_reduce(const float* __restrict__ vp, float* __restrict__ v,
                            int splitk)
{
    const int idx = blockIdx.x * 256 + threadIdx.x;   // covers 256*1040
    float s = 0.f;
    for (int k = 0; k < splitk; ++k) s += vp[(size_t)k * kNCol * kB + idx];
    v[idx] = s;
}

// W[b] = V1@V2@V3@V4@V5col; one 64-thr block per batch; v layout [b][col]
__global__ void fttv_chain(const float* __restrict__ v, float* __restrict__ w)
{
    const int b = blockIdx.x;
    const float* vb = v + (size_t)b * kNCol;
    const int lane = threadIdx.x;
    const int d = lane & 15;
    float u = vb[1024 + d];
    #pragma unroll
    for (int k = 4; k >= 1; --k) {
        float nu = 0.f;
        #pragma unroll
        for (int e = 0; e < 16; ++e) {
            const float ue = __shfl(u, e, 16);
            nu += vb[(k - 1) * 256 + d * 16 + e] * ue;
        }
        u = nu;
    }
    if (lane < 16) w[b * 16 + d] = u;
}

// out[b,s] = sum_d c0[s,d] * W[b,d]
__global__ __launch_bounds__(256) void fttv_out(
    const float* __restrict__ c0, const float* __restrict__ w,
    float* __restrict__ out)
{
    __shared__ float wl[64][16];
    const int sc = blockIdx.x & 63;
    const int bq = blockIdx.x >> 6;
    const int tid = threadIdx.x;
    const int s = sc * 256 + tid;
    float f0[16];
    #pragma unroll
    for (int q = 0; q < 4; ++q)
        *reinterpret_cast<float4*>(&f0[q * 4]) =
            *reinterpret_cast<const float4*>(c0 + (size_t)s * 16 + q * 4);
    *reinterpret_cast<float4*>(&wl[0][0] + tid * 4) =
        *reinterpret_cast<const float4*>(w + bq * 1024 + tid * 4);
    __syncthreads();
    for (int bb = 0; bb < 64; ++bb) {
        float a = 0.f;
        #pragma unroll
        for (int d = 0; d < 16; ++d) a += f0[d] * wl[bb][d];
        out[(size_t)(bq * 64 + bb) * kS + s] = a;
    }
}

// ---------------------------------------------------------------------------
extern "C" void kernel_launch(void* const* d_in, const int* in_sizes, int n_in,
                              void* d_out, int out_size, void* d_ws, size_t ws_size,
                              hipStream_t stream)
{
    (void)in_sizes; (void)n_in; (void)out_size;
    const float* z  = (const float*)d_in[0];
    const float* c0 = (const float*)d_in[1];
    const float* c1 = (const float*)d_in[2];
    const float* c2 = (const float*)d_in[3];
    const float* c3 = (const float*)d_in[4];
    const float* c4 = (const float*)d_in[5];
    const float* c5 = (const float*)d_in[6];
    float* out = (float*)d_out;
    float* ws  = (float*)d_ws;

    // ws: vp[splitk][256][1040] | v[256][1040] | w[256][16]
    int splitk = 32;
    while (splitk > 1 &&
           ((size_t)(splitk + 1) * kNCol * kB + (size_t)kB * 16) * sizeof(float) > ws_size)
        splitk >>= 1;
    const int kc = kS / splitk;   // multiple of 64 for splitk <= 256

    float* vp = ws;
    float* v  = vp + (size_t)splitk * kNCol * kB;
    float* w  = v + (size_t)kNCol * kB;

    fttv_gemm_mfma<<<dim3(18 * splitk), 256, 0, stream>>>(z, c1, c2, c3, c4, c5, vp, kc);
    fttv_reduce<<<dim3((kNCol * kB) / 256), 256, 0, stream>>>(vp, v, splitk);
    fttv_chain<<<dim3(kB), 64, 0, stream>>>(v, w);
    fttv_out<<<dim3(256), 256, 0, stream>>>(c0, w, out);
}